// Round 19
// baseline (389.946 us; speedup 1.0000x reference)
//
#include <hip/hip_runtime.h>
#include <cfloat>

#define NPTS 8192

typedef __attribute__((ext_vector_type(8))) short short8;
typedef __attribute__((ext_vector_type(4))) short short4v;
typedef __attribute__((ext_vector_type(4))) float f32x4;

__device__ inline unsigned short f2bf(float f) {
    unsigned u = __builtin_bit_cast(unsigned, f);
    u += 0x7fffu + ((u >> 16) & 1u);
    return (unsigned short)(u >> 16);
}
__device__ inline float bf2f(unsigned short h) {
    unsigned u = ((unsigned)h) << 16;
    return __builtin_bit_cast(float, u);
}

// ---------------------------------------------------------------------------
// Kernel 0: fused prep — bf16 weight conversion, candidate packing, fp32
// transposes of wq/wk/wv, AND zeroing the per-qsg completion counters.
// ---------------------------------------------------------------------------
__global__ void prep_kernel(const float* __restrict__ d2_w,
                            const float* __restrict__ g1_w,
                            const float* __restrict__ g2_w,
                            unsigned short* __restrict__ wd2,
                            unsigned short* __restrict__ wg1,
                            unsigned short* __restrict__ wg2,
                            const float* __restrict__ xyz,
                            float4* __restrict__ candp,
                            const float* __restrict__ wq_w,
                            const float* __restrict__ wk_w,
                            const float* __restrict__ wv_w,
                            float* __restrict__ wqT,
                            float* __restrict__ wkT,
                            float* __restrict__ wvT,
                            unsigned* __restrict__ qcnt)
{
    int i = blockIdx.x * 256 + threadIdx.x;          // 0 .. 114943
    if (i < 49152) {
        int sel = i >> 14, off = i & 16383;
        const float* s = (sel == 0) ? d2_w : (sel == 1) ? g1_w : g2_w;
        unsigned short* d = (sel == 0) ? wd2 : (sel == 1) ? wg1 : wg2;
        d[off] = f2bf(s[off]);
    } else if (i < 65536) {
        int j = i - 49152;                           // 0..16383
        int b = j >> 13, n = j & 8191;
        const float* xg = xyz + (long)b * 3 * NPTS;
        float x = xg[n], y = xg[NPTS + n], z = xg[2*NPTS + n];
        float4 c; c.x = x; c.y = y; c.z = z;
        c.w = fmaf(x, x, fmaf(y, y, z * z));
        candp[j] = c;
    } else if (i < 114688) {
        int idx = i - 65536;                         // 0..49151
        int sel = idx >> 14, off = idx & 16383;      // off = k*128 + c
        int k = off >> 7, c = off & 127;
        const float* s = (sel == 0) ? wq_w : (sel == 1) ? wk_w : wv_w;
        float* d = (sel == 0) ? wqT : (sel == 1) ? wkT : wvT;
        d[off] = s[c * 128 + k];
    } else if (i < 114944) {
        qcnt[i - 114688] = 0u;                       // 256 qsg counters
    }
}

// ---------------------------------------------------------------------------
// Kernel 1: UNION of knn_part (blocks 0..511) and proj (blocks 512..1023),
// with the top-16 MERGE FUSED via the canonical last-block pattern: after
// the select phase, each knn block threadfence()s, bumps a per-qsg counter;
// the second finisher acquires and rank-merges the 2x16 partials per query
// (identical (d,idx) ordering to the old merge kernel). Removes one kernel
// + one launch boundary. Pass-1 binning uses arithmetic-shift on signed
// bits (no fmax): negative/zero d clamps to bin 0 — same result.
// ---------------------------------------------------------------------------
#define KNB 120            // 15 octaves x 8 bins: dt in [2^-8, 2^7)
#define KBBASE 952         // (exp 119) << 3
#define KCAP 64            // survivor capacity per query per chunk

__global__ __launch_bounds__(512, 2)
void knn_proj_kernel(const float4* __restrict__ cand,
                     float* __restrict__ part_d, int* __restrict__ part_i,
                     unsigned* __restrict__ qcnt, int* __restrict__ knn,
                     const float* __restrict__ feat,
                     const float* __restrict__ fc1_w, const float* __restrict__ fc1_b,
                     const float* __restrict__ wqT, const float* __restrict__ wkT,
                     const float* __restrict__ wvT,
                     unsigned short* __restrict__ qb,
                     unsigned short* __restrict__ kbuf,
                     unsigned short* __restrict__ vbuf)
{
    __shared__ union {
        struct {
            unsigned hist[KNB * 64];   // [bin][query] u32 counts
            float2   surv[64 * 65];    // [query][slot] (dt, idx-bits)
            unsigned scnt[64];
            int      bthr[64];
        } k;
        struct {
            float fl[32][3];
            float xl[32][128];
        } p;
    } sm;
    __shared__ unsigned lastFlag;

    const int t = threadIdx.x;

    if (blockIdx.x < 512) {
        // ================= KNN branch =================
        unsigned* hist = sm.k.hist;
        float2*   surv = sm.k.surv;
        unsigned* scnt = sm.k.scnt;
        int*      bthr = sm.k.bthr;

        const int ql = t & 63, wv = t >> 6;
        const int wv_u = __builtin_amdgcn_readfirstlane(wv);
        const int qsg = blockIdx.x >> 1;      // 0..255 query group
        const int ck  = blockIdx.x & 1;       // chunk of 4096
        const int b_u = qsg >> 7;             // batch id, block-uniform
        const int q   = qsg * 64 + ql;        // global query id
        const int n   = q & 8191;

        const float4* cp = cand + (b_u << 13) + ck * 4096 + wv_u * 512;
        const int ibase = ck * 4096 + wv_u * 512;
        float4 qc = cand[(b_u << 13) + n];
        const float qx2 = -2.f * qc.x, qy2 = -2.f * qc.y, qz2 = -2.f * qc.z;
        const float qw = qc.w;

        for (int i = t; i < KNB * 64; i += 512) hist[i] = 0u;
        if (t < 64) scnt[t] = 0u;
        __syncthreads();

        auto dtil = [&](float4 c) {
            return fmaf(qx2, c.x, fmaf(qy2, c.y, fmaf(qz2, c.z, c.w + qw)));
        };
        auto binOf = [&](float d) {
            int sb = __builtin_bit_cast(int, d);
            int b = (sb >> 20) - KBBASE;          // arithmetic shift: d<=0 -> <0
            return b < 0 ? 0 : (b > (KNB - 1) ? (KNB - 1) : b);
        };

        // pass 1: histogram
        {
            unsigned* hq = hist + ql;
            float4 A[8], Bv[8];
            #pragma unroll
            for (int u = 0; u < 8; ++u) A[u] = cp[u];
            for (int m = 0; m < 512; m += 16) {
                #pragma unroll
                for (int u = 0; u < 8; ++u) Bv[u] = cp[m + 8 + u];
                #pragma unroll
                for (int u = 0; u < 8; ++u) {
                    int bb = binOf(dtil(A[u]));
                    atomicAdd(hq + bb * 64, 1u);
                }
                if (m + 16 < 512) {
                    #pragma unroll
                    for (int u = 0; u < 8; ++u) A[u] = cp[m + 16 + u];
                }
                #pragma unroll
                for (int u = 0; u < 8; ++u) {
                    int bb = binOf(dtil(Bv[u]));
                    atomicAdd(hq + bb * 64, 1u);
                }
            }
        }
        __syncthreads();

        // threshold scan
        if (t < 64) {
            int cum = 0, bs = 0;
            #pragma unroll 8
            for (int b = 0; b < KNB; ++b) {
                cum += (int)hist[b * 64 + t];
                bs += (cum < 16) ? 1 : 0;
            }
            bthr[t] = (bs >= KNB - 1) ? 0x7FFFFFFF : ((bs + KBBASE + 1) << 20);
        }
        __syncthreads();

        // pass 2: collect survivors
        {
            const int mythr = bthr[ql];
            float4 A[8], Bv[8];
            #pragma unroll
            for (int u = 0; u < 8; ++u) A[u] = cp[u];
            for (int m = 0; m < 512; m += 16) {
                #pragma unroll
                for (int u = 0; u < 8; ++u) Bv[u] = cp[m + 8 + u];
                #pragma unroll
                for (int u = 0; u < 8; ++u) {
                    float d = dtil(A[u]);
                    if (__builtin_bit_cast(int, d) < mythr) {
                        unsigned s = atomicAdd(&scnt[ql], 1u);
                        if (s < (unsigned)KCAP) {
                            float2 e; e.x = d;
                            e.y = __builtin_bit_cast(float, ibase + m + u);
                            surv[ql * 65 + s] = e;
                        }
                    }
                }
                if (m + 16 < 512) {
                    #pragma unroll
                    for (int u = 0; u < 8; ++u) A[u] = cp[m + 16 + u];
                }
                #pragma unroll
                for (int u = 0; u < 8; ++u) {
                    float d = dtil(Bv[u]);
                    if (__builtin_bit_cast(int, d) < mythr) {
                        unsigned s = atomicAdd(&scnt[ql], 1u);
                        if (s < (unsigned)KCAP) {
                            float2 e; e.x = d;
                            e.y = __builtin_bit_cast(float, ibase + m + 8 + u);
                            surv[ql * 65 + s] = e;
                        }
                    }
                }
            }
        }
        __syncthreads();

        // exact select -> partial top-16 for this chunk
        {
            const int q2 = t >> 3;
            const int s0 = t & 7;
            const unsigned cnt = min(scnt[q2], (unsigned)KCAP);
            const float2* sp = surv + q2 * 65;
            const long pb = ((long)(qsg * 64 + q2)) * 32 + ck * 16;
            for (unsigned s = s0; s < cnt; s += 8) {
                float2 e = sp[s];
                float d = e.x;
                int idx = __builtin_bit_cast(int, e.y);
                int rank = 0;
                #pragma unroll 8
                for (unsigned j = 0; j < cnt; ++j) {
                    float2 f = sp[j];
                    float dj = f.x;
                    int ij = __builtin_bit_cast(int, f.y);
                    rank += ((dj < d) || (dj == d && ij < idx)) ? 1 : 0;
                }
                if (rank < 16) {
                    part_d[pb + rank] = d;
                    part_i[pb + rank] = idx;
                }
            }
        }

        // ---- fused merge: last block of this qsg merges 2x16 -> top-16 ----
        __syncthreads();
        __threadfence();                      // release this block's partials
        __syncthreads();
        if (t == 0) lastFlag = atomicAdd(&qcnt[qsg], 1u);
        __syncthreads();
        if (lastFlag == 1u) {
            __threadfence();                  // acquire: invalidate stale L2
            float* msd = reinterpret_cast<float*>(sm.k.surv);          // [64][33]
            int*   msi = reinterpret_cast<int*>(sm.k.surv + 1100);     // [64][33]
            // cooperative load: 2048 entries
            for (int eg = t; eg < 2048; eg += 512) {
                int q2 = eg >> 5, sl = eg & 31;
                long gp = ((long)(qsg * 64 + q2)) * 32 + sl;
                msd[q2 * 33 + sl] = part_d[gp];
                msi[q2 * 33 + sl] = part_i[gp];
            }
            __syncthreads();
            const int q2 = t >> 3, s0 = t & 7;
            #pragma unroll
            for (int j4 = 0; j4 < 4; ++j4) {
                int sl = s0 + j4 * 8;
                float d = msd[q2 * 33 + sl];
                int idx = msi[q2 * 33 + sl];
                int rank = 0;
                #pragma unroll
                for (int j = 0; j < 32; ++j) {
                    float dj = msd[q2 * 33 + j];
                    rank += ((dj < d) || (dj == d && msi[q2 * 33 + j] < idx)) ? 1 : 0;
                }
                if (rank < 16) knn[(long)(qsg * 64 + q2) * 16 + rank] = idx;
            }
        }
    } else {
        // ================= PROJ branch (R10 numerics, 32 pts/block) ======
        float (*fl)[3]   = sm.p.fl;
        float (*xl)[128] = sm.p.xl;

        const int tc = t & 127;               // channel 0..127
        const int pg = t >> 7;                // point-group 0..3
        const long base = (long)(blockIdx.x - 512) * 32 + pg * 8;

        if (tc < 24) {
            int p = tc / 3, d = tc % 3;
            long pt = base + p;
            int b = (int)(pt >> 13), n = (int)(pt & 8191);
            fl[pg*8 + p][d] = feat[((long)b * 3 + d) * NPTS + n];
        }
        __syncthreads();

        float w0 = fc1_w[tc*3+0], w1 = fc1_w[tc*3+1], w2 = fc1_w[tc*3+2];
        float b0 = fc1_b[tc];
        #pragma unroll
        for (int p = 0; p < 8; ++p)
            xl[pg*8 + p][tc] = fmaf(w0, fl[pg*8+p][0],
                               fmaf(w1, fl[pg*8+p][1],
                               fmaf(w2, fl[pg*8+p][2], b0)));
        __syncthreads();

        float aq[8], ak[8], av[8];
        #pragma unroll
        for (int p = 0; p < 8; ++p) { aq[p] = 0.f; ak[p] = 0.f; av[p] = 0.f; }

        for (int i4 = 0; i4 < 32; ++i4) {
            const int k0 = i4 * 4;
            float qa = wqT[(k0+0)*128 + tc], qbw = wqT[(k0+1)*128 + tc];
            float qc2 = wqT[(k0+2)*128 + tc], qd = wqT[(k0+3)*128 + tc];
            float ka = wkT[(k0+0)*128 + tc], kbw = wkT[(k0+1)*128 + tc];
            float kc2 = wkT[(k0+2)*128 + tc], kd = wkT[(k0+3)*128 + tc];
            float va = wvT[(k0+0)*128 + tc], vbw = wvT[(k0+1)*128 + tc];
            float vc2 = wvT[(k0+2)*128 + tc], vd = wvT[(k0+3)*128 + tc];
            #pragma unroll
            for (int p = 0; p < 8; ++p) {
                float4 x = *(const float4*)&xl[pg*8 + p][k0];
                aq[p] = fmaf(qa,x.x, fmaf(qbw,x.y, fmaf(qc2,x.z, fmaf(qd,x.w, aq[p]))));
                ak[p] = fmaf(ka,x.x, fmaf(kbw,x.y, fmaf(kc2,x.z, fmaf(kd,x.w, ak[p]))));
                av[p] = fmaf(va,x.x, fmaf(vbw,x.y, fmaf(vc2,x.z, fmaf(vd,x.w, av[p]))));
            }
        }
        const int perm = (tc & 15) * 8 + (tc >> 4);
        #pragma unroll
        for (int p = 0; p < 8; ++p) {
            long pt = base + p;
            qb[pt*128 + perm]   = f2bf(aq[p]);
            kbuf[pt*128 + perm] = f2bf(ak[p]);
            vbuf[pt*128 + perm] = f2bf(av[p]);
        }
    }
}

// ---------------------------------------------------------------------------
// Kernel 2: fused attention v9 (R18 verbatim — 4-wave-packed, LDS-staged
// weights, proven winner: attn dropped below 111us).
// ---------------------------------------------------------------------------
__device__ inline int hswz(int r, int c) {           // hbuf swizzled index
    return r * 128 + (c ^ ((r & 7) << 4));
}
__device__ inline int wswz(int r, int c) {           // wbuf swizzled index
    return r * 128 + (c ^ ((r & 7) << 3));
}

__global__ __launch_bounds__(256, 2)
void attn_kernel(const float* __restrict__ xyz, const float* __restrict__ feat,
                 const float* __restrict__ d1_w, const float* __restrict__ d1_b,
                 const float* __restrict__ d2_b, const float* __restrict__ g1_b,
                 const float* __restrict__ g2_b,
                 const float* __restrict__ fc2_w, const float* __restrict__ fc2_b,
                 const unsigned short* __restrict__ qb,
                 const unsigned short* __restrict__ kb,
                 const unsigned short* __restrict__ vb,
                 const unsigned short* __restrict__ wd2,
                 const unsigned short* __restrict__ wg1,
                 const unsigned short* __restrict__ wg2,
                 const int* __restrict__ knn, float* __restrict__ out)
{
    __shared__ unsigned short hbuf_all[4][32 * 128];  // per-wave private slice
    __shared__ unsigned short wbuf[128 * 128];        // shared weight stage

    const int wave = threadIdx.x >> 6;
    const int lane = threadIdx.x & 63;
    unsigned short* hbuf = hbuf_all[wave];

    const int quad = lane >> 4, l15 = lane & 15;
    const long pbase = (long)blockIdx.x * 8 + wave * 2;
    const int b = (int)(pbase >> 13);
    const long bofs = (long)b * NPTS;

    auto stageW = [&](const unsigned short* w) {
        #pragma unroll
        for (int it = 0; it < 8; ++it) {
            int cidx = (int)threadIdx.x + it * 256;   // 0..2047
            int row = cidx >> 4, c8 = (cidx & 15) << 3;
            short8 v = *(const short8*)(w + cidx * 8);
            *(short8*)&wbuf[wswz(row, c8)] = v;
        }
    };

    // lanes<32: neighbor index + rel vector for row `lane`
    int m = 0; float rx = 0.f, ry = 0.f, rz = 0.f;
    if (lane < 32) {
        m = knn[(pbase + (lane >> 4)) * 16 + (lane & 15)];
        int nn = (int)((pbase + (lane >> 4)) & 8191);
        const float* xg = xyz + (long)b * 3 * NPTS;
        rx = xg[nn]        - xg[m];
        ry = xg[NPTS+nn]   - xg[NPTS+m];
        rz = xg[2*NPTS+nn] - xg[2*NPTS+m];
    }

    // per-lane gather offsets into kb/vb (u16 elements), via shuffle
    int koff[8];
    #pragma unroll
    for (int mt = 0; mt < 2; ++mt)
        #pragma unroll
        for (int r = 0; r < 4; ++r) {
            int idxm = __shfl(m, mt*16 + quad*4 + r);
            koff[mt*4 + r] = (int)(bofs + idxm) * 128 + l15*8;
        }

    // K gather + q load early
    short8 qvv[2], kgv[2][4], vgv[2][4];
    #pragma unroll
    for (int mt = 0; mt < 2; ++mt) {
        qvv[mt] = *(const short8*)(qb + (size_t)(pbase + mt) * 128 + l15*8);
        #pragma unroll
        for (int r = 0; r < 4; ++r)
            kgv[mt][r] = *(const short8*)(kb + koff[mt*4 + r]);
    }

    // stage wd2 while gathers are in flight
    stageW(wd2);

    // h1 = relu(rel @ d1.T + b)
    {
        float w0[8], w1[8], w2[8], bb[8];
        #pragma unroll
        for (int k = 0; k < 8; ++k) {
            int c = l15*8 + k;
            w0[k] = d1_w[c*3]; w1[k] = d1_w[c*3+1]; w2[k] = d1_w[c*3+2];
            bb[k] = d1_b[c];
        }
        #pragma unroll
        for (int i = 0; i < 8; ++i) {
            int row = quad + 4*i;
            float sx = __shfl(rx, row), sy = __shfl(ry, row), sz = __shfl(rz, row);
            short8 hv;
            #pragma unroll
            for (int k = 0; k < 8; ++k) {
                float v = fmaf(w0[k], sx, fmaf(w1[k], sy, fmaf(w2[k], sz, bb[k])));
                hv[k] = (short)f2bf(fmaxf(v, 0.f));
            }
            *(short8*)&hbuf[hswz(row, l15*8)] = hv;
        }
    }
    __syncthreads();   // wd2 staged + h1 written

    short8 A[2][4];
    f32x4 acc[2];

    auto loadA = [&]() {
        #pragma unroll
        for (int mt = 0; mt < 2; ++mt)
            #pragma unroll
            for (int kk = 0; kk < 4; ++kk)
                A[mt][kk] = *(const short8*)&hbuf[hswz(mt*16 + l15, kk*32 + quad*8)];
    };
    auto loadB = [&](int n0, short8& B0, short8& B1, short8& B2, short8& B3) {
        int r = n0*16 + l15;
        B0 = *(const short8*)&wbuf[wswz(r, quad*8)];
        B1 = *(const short8*)&wbuf[wswz(r, quad*8 + 32)];
        B2 = *(const short8*)&wbuf[wswz(r, quad*8 + 64)];
        B3 = *(const short8*)&wbuf[wswz(r, quad*8 + 96)];
    };

    unsigned posp[2][8][2];   // packed bf16 pos fragments

    // ============ GEMM 1: pos = h1 @ d2.T + b; h = q - kg + pos ============
    loadA();
    #pragma unroll
    for (int n0 = 0; n0 < 8; ++n0) {
        short8 B0, B1, B2, B3;
        loadB(n0, B0, B1, B2, B3);
        acc[0] = (f32x4){0.f,0.f,0.f,0.f};
        acc[1] = (f32x4){0.f,0.f,0.f,0.f};
        __builtin_amdgcn_s_setprio(1);
        #pragma unroll
        for (int mt = 0; mt < 2; ++mt) {
            acc[mt] = __builtin_amdgcn_mfma_f32_16x16x32_bf16(A[mt][0], B0, acc[mt], 0, 0, 0);
            acc[mt] = __builtin_amdgcn_mfma_f32_16x16x32_bf16(A[mt][1], B1, acc[mt], 0, 0, 0);
            acc[mt] = __builtin_amdgcn_mfma_f32_16x16x32_bf16(A[mt][2], B2, acc[mt], 0, 0, 0);
            acc[mt] = __builtin_amdgcn_mfma_f32_16x16x32_bf16(A[mt][3], B3, acc[mt], 0, 0, 0);
        }
        __builtin_amdgcn_s_setprio(0);
        int c = n0*16 + l15;
        float bb = d2_b[c];
        #pragma unroll
        for (int mt = 0; mt < 2; ++mt) {
            float qv = bf2f((unsigned short)qvv[mt][n0]);
            float p0 = acc[mt][0] + bb, p1 = acc[mt][1] + bb;
            float p2 = acc[mt][2] + bb, p3 = acc[mt][3] + bb;
            posp[mt][n0][0] = (unsigned)f2bf(p0) | ((unsigned)f2bf(p1) << 16);
            posp[mt][n0][1] = (unsigned)f2bf(p2) | ((unsigned)f2bf(p3) << 16);
            int rb = mt*16 + quad*4;
            hbuf[hswz(rb+0, c)] = f2bf(qv - bf2f((unsigned short)kgv[mt][0][n0]) + p0);
            hbuf[hswz(rb+1, c)] = f2bf(qv - bf2f((unsigned short)kgv[mt][1][n0]) + p1);
            hbuf[hswz(rb+2, c)] = f2bf(qv - bf2f((unsigned short)kgv[mt][2][n0]) + p2);
            hbuf[hswz(rb+3, c)] = f2bf(qv - bf2f((unsigned short)kgv[mt][3][n0]) + p3);
        }
    }
    __syncthreads();          // all waves done reading wd2
    stageW(wg1);
    __syncthreads();          // wg1 staged

    // ============ GEMM 2: gh = relu(h @ g1.T + b) ============
    loadA();
    #pragma unroll
    for (int n0 = 0; n0 < 8; ++n0) {
        short8 B0, B1, B2, B3;
        loadB(n0, B0, B1, B2, B3);
        acc[0] = (f32x4){0.f,0.f,0.f,0.f};
        acc[1] = (f32x4){0.f,0.f,0.f,0.f};
        __builtin_amdgcn_s_setprio(1);
        #pragma unroll
        for (int mt = 0; mt < 2; ++mt) {
            acc[mt] = __builtin_amdgcn_mfma_f32_16x16x32_bf16(A[mt][0], B0, acc[mt], 0, 0, 0);
            acc[mt] = __builtin_amdgcn_mfma_f32_16x16x32_bf16(A[mt][1], B1, acc[mt], 0, 0, 0);
            acc[mt] = __builtin_amdgcn_mfma_f32_16x16x32_bf16(A[mt][2], B2, acc[mt], 0, 0, 0);
            acc[mt] = __builtin_amdgcn_mfma_f32_16x16x32_bf16(A[mt][3], B3, acc[mt], 0, 0, 0);
        }
        __builtin_amdgcn_s_setprio(0);
        int c = n0*16 + l15;
        float bb = g1_b[c];
        #pragma unroll
        for (int mt = 0; mt < 2; ++mt) {
            int rb = mt*16 + quad*4;
            #pragma unroll
            for (int r = 0; r < 4; ++r)
                hbuf[hswz(rb+r, c)] = f2bf(fmaxf(acc[mt][r] + bb, 0.f));
        }
    }
    __syncthreads();          // all waves done reading wg1
    stageW(wg2);

    // deferred V gather (only needed by GEMM 3)
    #pragma unroll
    for (int mt = 0; mt < 2; ++mt)
        #pragma unroll
        for (int r = 0; r < 4; ++r)
            vgv[mt][r] = *(const short8*)(vb + koff[mt*4 + r]);
    __syncthreads();          // wg2 staged

    // ==== GEMM 3: logits -> softmax over K -> res -> fused fc2 epilogue ====
    loadA();
    const float sc = 0.08838834764831845f;
    float pr[2][3];
    #pragma unroll
    for (int mt = 0; mt < 2; ++mt) { pr[mt][0] = 0.f; pr[mt][1] = 0.f; pr[mt][2] = 0.f; }
    #pragma unroll
    for (int n0 = 0; n0 < 8; ++n0) {
        short8 B0, B1, B2, B3;
        loadB(n0, B0, B1, B2, B3);
        acc[0] = (f32x4){0.f,0.f,0.f,0.f};
        acc[1] = (f32x4){0.f,0.f,0.f,0.f};
        __builtin_amdgcn_s_setprio(1);
        #pragma unroll
        for (int mt = 0; mt < 2; ++mt) {
            acc[mt] = __builtin_amdgcn_mfma_f32_16x16x32_bf16(A[mt][0], B0, acc[mt], 0, 0, 0);
            acc[mt] = __builtin_amdgcn_mfma_f32_16x16x32_bf16(A[mt][1], B1, acc[mt], 0, 0, 0);
            acc[mt] = __builtin_amdgcn_mfma_f32_16x16x32_bf16(A[mt][2], B2, acc[mt], 0, 0, 0);
            acc[mt] = __builtin_amdgcn_mfma_f32_16x16x32_bf16(A[mt][3], B3, acc[mt], 0, 0, 0);
        }
        __builtin_amdgcn_s_setprio(0);
        int c = n0*16 + l15;
        float bb = g2_b[c];
        float f0 = fc2_w[c];
        float f1 = fc2_w[128 + c];
        float f2 = fc2_w[256 + c];
        #pragma unroll
        for (int mt = 0; mt < 2; ++mt) {
            float e0 = (acc[mt][0] + bb) * sc;
            float e1 = (acc[mt][1] + bb) * sc;
            float e2 = (acc[mt][2] + bb) * sc;
            float e3 = (acc[mt][3] + bb) * sc;
            float mx = fmaxf(fmaxf(e0, e1), fmaxf(e2, e3));
            mx = fmaxf(mx, __shfl_xor(mx, 16));
            mx = fmaxf(mx, __shfl_xor(mx, 32));
            e0 = __expf(e0 - mx); e1 = __expf(e1 - mx);
            e2 = __expf(e2 - mx); e3 = __expf(e3 - mx);
            float ssum = e0 + e1 + e2 + e3;
            ssum += __shfl_xor(ssum, 16);
            ssum += __shfl_xor(ssum, 32);
            float p0 = bf2f((unsigned short)(posp[mt][n0][0] & 0xffff));
            float p1 = bf2f((unsigned short)(posp[mt][n0][0] >> 16));
            float p2 = bf2f((unsigned short)(posp[mt][n0][1] & 0xffff));
            float p3 = bf2f((unsigned short)(posp[mt][n0][1] >> 16));
            float p = e0 * (bf2f((unsigned short)vgv[mt][0][n0]) + p0)
                    + e1 * (bf2f((unsigned short)vgv[mt][1][n0]) + p1)
                    + e2 * (bf2f((unsigned short)vgv[mt][2][n0]) + p2)
                    + e3 * (bf2f((unsigned short)vgv[mt][3][n0]) + p3);
            p += __shfl_xor(p, 16);
            p += __shfl_xor(p, 32);
            float rres = p / ssum;                 // replicated across quads
            pr[mt][0] = fmaf(f0, rres, pr[mt][0]);
            pr[mt][1] = fmaf(f1, rres, pr[mt][1]);
            pr[mt][2] = fmaf(f2, rres, pr[mt][2]);
        }
    }

    // reduce fc2 partials over l15 (quads are replicas) and store
    #pragma unroll
    for (int mt = 0; mt < 2; ++mt) {
        float pr0 = pr[mt][0], pr1 = pr[mt][1], pr2 = pr[mt][2];
        #pragma unroll
        for (int s2 = 1; s2 <= 8; s2 <<= 1) {
            pr0 += __shfl_xor(pr0, s2);
            pr1 += __shfl_xor(pr1, s2);
            pr2 += __shfl_xor(pr2, s2);
        }
        int nn = (int)((pbase + mt) & 8191);
        if (lane < 3) {
            float pv = (lane == 0) ? pr0 : (lane == 1) ? pr1 : pr2;
            long o = ((long)b*3 + lane) * NPTS + nn;
            out[o] = pv + fc2_b[lane] + feat[o];
        }
    }
}

// ---------------------------------------------------------------------------
extern "C" void kernel_launch(void* const* d_in, const int* in_sizes, int n_in,
                              void* d_out, int out_size, void* d_ws, size_t ws_size,
                              hipStream_t stream)
{
    const float* xyz   = (const float*)d_in[0];
    const float* feat  = (const float*)d_in[1];
    const float* fc1_w = (const float*)d_in[2];
    const float* fc1_b = (const float*)d_in[3];
    const float* fc2_w = (const float*)d_in[4];
    const float* fc2_b = (const float*)d_in[5];
    const float* d1_w  = (const float*)d_in[6];
    const float* d1_b  = (const float*)d_in[7];
    const float* d2_w  = (const float*)d_in[8];
    const float* d2_b  = (const float*)d_in[9];
    const float* g1_w  = (const float*)d_in[10];
    const float* g1_b  = (const float*)d_in[11];
    const float* g2_w  = (const float*)d_in[12];
    const float* g2_b  = (const float*)d_in[13];
    const float* wq_w  = (const float*)d_in[14];
    const float* wk_w  = (const float*)d_in[15];
    const float* wv_w  = (const float*)d_in[16];
    float* out = (float*)d_out;

    unsigned short* qb  = (unsigned short*)d_ws;      // 16384*128 bf16 (permuted)
    unsigned short* kb  = qb + (size_t)16384*128;
    unsigned short* vb  = kb + (size_t)16384*128;
    unsigned short* wd2 = vb + (size_t)16384*128;     // 128*128 bf16 each
    unsigned short* wg1 = wd2 + 16384;
    unsigned short* wg2 = wg1 + 16384;
    int*   knn_ws = (int*)(wg2 + 16384);              // 16384*16 i32
    float4* cand  = (float4*)(knn_ws + (size_t)16384*16);   // 16384 float4
    float* part_d = (float*)(cand + 16384);           // [0, 16384*32) used by knn
    int*   part_i = (int*)(part_d + (size_t)16384*64);// [0, 16384*32) used by knn
    // wqT/wkT/wvT live in the UNUSED upper half of part_d; qcnt in the
    // unused upper half of part_i — no workspace extension.
    float* wqT    = part_d + (size_t)16384*32;        // 128*128 f32 each
    float* wkT    = wqT + 16384;
    float* wvT    = wkT + 16384;
    unsigned* qcnt = (unsigned*)(part_i + (size_t)16384*32);  // 256 counters

    hipLaunchKernelGGL(prep_kernel, dim3(449), dim3(256), 0, stream,
                       d2_w, g1_w, g2_w, wd2, wg1, wg2, xyz, cand,
                       wq_w, wk_w, wv_w, wqT, wkT, wvT, qcnt);
    hipLaunchKernelGGL(knn_proj_kernel, dim3(1024), dim3(512), 0, stream,
                       cand, part_d, part_i, qcnt, knn_ws,
                       feat, fc1_w, fc1_b, wqT, wkT, wvT, qb, kb, vb);
    hipLaunchKernelGGL(attn_kernel, dim3(2048), dim3(256), 0, stream,
                       xyz, feat, d1_w, d1_b, d2_b, g1_b, g2_b, fc2_w, fc2_b,
                       qb, kb, vb, wd2, wg1, wg2, knn_ws, out);
}

// Round 20
// 260.112 us; speedup vs baseline: 1.4992x; 1.4992x over previous
//
#include <hip/hip_runtime.h>
#include <cfloat>

#define NPTS 8192

typedef __attribute__((ext_vector_type(8))) short short8;
typedef __attribute__((ext_vector_type(4))) short short4v;
typedef __attribute__((ext_vector_type(4))) float f32x4;

__device__ inline unsigned short f2bf(float f) {
    unsigned u = __builtin_bit_cast(unsigned, f);
    u += 0x7fffu + ((u >> 16) & 1u);
    return (unsigned short)(u >> 16);
}
__device__ inline float bf2f(unsigned short h) {
    unsigned u = ((unsigned)h) << 16;
    return __builtin_bit_cast(float, u);
}

// ---------------------------------------------------------------------------
// Kernel 0: fused prep — bf16 weight conversion, candidate packing, AND
// fp32 transposes of wq/wk/wv to [k][c] layout for coalesced proj loads.
// ---------------------------------------------------------------------------
__global__ void prep_kernel(const float* __restrict__ d2_w,
                            const float* __restrict__ g1_w,
                            const float* __restrict__ g2_w,
                            unsigned short* __restrict__ wd2,
                            unsigned short* __restrict__ wg1,
                            unsigned short* __restrict__ wg2,
                            const float* __restrict__ xyz,
                            float4* __restrict__ candp,
                            const float* __restrict__ wq_w,
                            const float* __restrict__ wk_w,
                            const float* __restrict__ wv_w,
                            float* __restrict__ wqT,
                            float* __restrict__ wkT,
                            float* __restrict__ wvT)
{
    int i = blockIdx.x * 256 + threadIdx.x;          // 0 .. 114687
    if (i < 49152) {
        int sel = i >> 14, off = i & 16383;
        const float* s = (sel == 0) ? d2_w : (sel == 1) ? g1_w : g2_w;
        unsigned short* d = (sel == 0) ? wd2 : (sel == 1) ? wg1 : wg2;
        d[off] = f2bf(s[off]);
    } else if (i < 65536) {
        int j = i - 49152;                           // 0..16383
        int b = j >> 13, n = j & 8191;
        const float* xg = xyz + (long)b * 3 * NPTS;
        float x = xg[n], y = xg[NPTS + n], z = xg[2*NPTS + n];
        float4 c; c.x = x; c.y = y; c.z = z;
        c.w = fmaf(x, x, fmaf(y, y, z * z));
        candp[j] = c;
    } else if (i < 114688) {
        int idx = i - 65536;                         // 0..49151
        int sel = idx >> 14, off = idx & 16383;      // off = k*128 + c
        int k = off >> 7, c = off & 127;
        const float* s = (sel == 0) ? wq_w : (sel == 1) ? wk_w : wv_w;
        float* d = (sel == 0) ? wqT : (sel == 1) ? wkT : wvT;
        d[off] = s[c * 128 + k];
    }
}

// ---------------------------------------------------------------------------
// Kernel 1: UNION of knn_part (blocks 0..511) and proj (blocks 512..1023).
// R18 verbatim (R19's last-block fused merge regressed 111->250us: the
// device-scope threadfence in every knn block serializes across the 8
// non-coherent XCD L2s — merge stays a separate kernel). binOf uses the
// R19-harness-proven arithmetic-shift form (1 VALU cheaper, bit-identical).
// ---------------------------------------------------------------------------
#define KNB 120            // 15 octaves x 8 bins: dt in [2^-8, 2^7)
#define KBBASE 952         // (exp 119) << 3
#define KCAP 64            // survivor capacity per query per chunk

__global__ __launch_bounds__(512, 2)
void knn_proj_kernel(const float4* __restrict__ cand,
                     float* __restrict__ part_d, int* __restrict__ part_i,
                     const float* __restrict__ feat,
                     const float* __restrict__ fc1_w, const float* __restrict__ fc1_b,
                     const float* __restrict__ wqT, const float* __restrict__ wkT,
                     const float* __restrict__ wvT,
                     unsigned short* __restrict__ qb,
                     unsigned short* __restrict__ kbuf,
                     unsigned short* __restrict__ vbuf)
{
    __shared__ union {
        struct {
            unsigned hist[KNB * 64];   // [bin][query] u32 counts
            float2   surv[64 * 65];    // [query][slot] (dt, idx-bits)
            unsigned scnt[64];
            int      bthr[64];
        } k;
        struct {
            float fl[32][3];
            float xl[32][128];
        } p;
    } sm;

    const int t = threadIdx.x;

    if (blockIdx.x < 512) {
        // ================= KNN branch =================
        unsigned* hist = sm.k.hist;
        float2*   surv = sm.k.surv;
        unsigned* scnt = sm.k.scnt;
        int*      bthr = sm.k.bthr;

        const int ql = t & 63, wv = t >> 6;
        const int wv_u = __builtin_amdgcn_readfirstlane(wv);
        const int qsg = blockIdx.x >> 1;      // 0..255 query group
        const int ck  = blockIdx.x & 1;       // chunk of 4096
        const int b_u = qsg >> 7;             // batch id, block-uniform
        const int q   = qsg * 64 + ql;        // global query id
        const int n   = q & 8191;

        const float4* cp = cand + (b_u << 13) + ck * 4096 + wv_u * 512;
        const int ibase = ck * 4096 + wv_u * 512;
        float4 qc = cand[(b_u << 13) + n];
        const float qx2 = -2.f * qc.x, qy2 = -2.f * qc.y, qz2 = -2.f * qc.z;
        const float qw = qc.w;

        for (int i = t; i < KNB * 64; i += 512) hist[i] = 0u;
        if (t < 64) scnt[t] = 0u;
        __syncthreads();

        auto dtil = [&](float4 c) {
            return fmaf(qx2, c.x, fmaf(qy2, c.y, fmaf(qz2, c.z, c.w + qw)));
        };
        auto binOf = [&](float d) {
            int sb = __builtin_bit_cast(int, d);
            int b = (sb >> 20) - KBBASE;          // arithmetic shift: d<=0 -> <0
            return b < 0 ? 0 : (b > (KNB - 1) ? (KNB - 1) : b);
        };

        // pass 1: histogram
        {
            unsigned* hq = hist + ql;
            float4 A[8], Bv[8];
            #pragma unroll
            for (int u = 0; u < 8; ++u) A[u] = cp[u];
            for (int m = 0; m < 512; m += 16) {
                #pragma unroll
                for (int u = 0; u < 8; ++u) Bv[u] = cp[m + 8 + u];
                #pragma unroll
                for (int u = 0; u < 8; ++u) {
                    int bb = binOf(dtil(A[u]));
                    atomicAdd(hq + bb * 64, 1u);
                }
                if (m + 16 < 512) {
                    #pragma unroll
                    for (int u = 0; u < 8; ++u) A[u] = cp[m + 16 + u];
                }
                #pragma unroll
                for (int u = 0; u < 8; ++u) {
                    int bb = binOf(dtil(Bv[u]));
                    atomicAdd(hq + bb * 64, 1u);
                }
            }
        }
        __syncthreads();

        // threshold scan
        if (t < 64) {
            int cum = 0, bs = 0;
            #pragma unroll 8
            for (int b = 0; b < KNB; ++b) {
                cum += (int)hist[b * 64 + t];
                bs += (cum < 16) ? 1 : 0;
            }
            bthr[t] = (bs >= KNB - 1) ? 0x7FFFFFFF : ((bs + KBBASE + 1) << 20);
        }
        __syncthreads();

        // pass 2: collect survivors
        {
            const int mythr = bthr[ql];
            float4 A[8], Bv[8];
            #pragma unroll
            for (int u = 0; u < 8; ++u) A[u] = cp[u];
            for (int m = 0; m < 512; m += 16) {
                #pragma unroll
                for (int u = 0; u < 8; ++u) Bv[u] = cp[m + 8 + u];
                #pragma unroll
                for (int u = 0; u < 8; ++u) {
                    float d = dtil(A[u]);
                    if (__builtin_bit_cast(int, d) < mythr) {
                        unsigned s = atomicAdd(&scnt[ql], 1u);
                        if (s < (unsigned)KCAP) {
                            float2 e; e.x = d;
                            e.y = __builtin_bit_cast(float, ibase + m + u);
                            surv[ql * 65 + s] = e;
                        }
                    }
                }
                if (m + 16 < 512) {
                    #pragma unroll
                    for (int u = 0; u < 8; ++u) A[u] = cp[m + 16 + u];
                }
                #pragma unroll
                for (int u = 0; u < 8; ++u) {
                    float d = dtil(Bv[u]);
                    if (__builtin_bit_cast(int, d) < mythr) {
                        unsigned s = atomicAdd(&scnt[ql], 1u);
                        if (s < (unsigned)KCAP) {
                            float2 e; e.x = d;
                            e.y = __builtin_bit_cast(float, ibase + m + 8 + u);
                            surv[ql * 65 + s] = e;
                        }
                    }
                }
            }
        }
        __syncthreads();

        // exact select
        {
            const int q2 = t >> 3;
            const int s0 = t & 7;
            const unsigned cnt = min(scnt[q2], (unsigned)KCAP);
            const float2* sp = surv + q2 * 65;
            const long pb = ((long)(qsg * 64 + q2)) * 32 + ck * 16;
            for (unsigned s = s0; s < cnt; s += 8) {
                float2 e = sp[s];
                float d = e.x;
                int idx = __builtin_bit_cast(int, e.y);
                int rank = 0;
                #pragma unroll 8
                for (unsigned j = 0; j < cnt; ++j) {
                    float2 f = sp[j];
                    float dj = f.x;
                    int ij = __builtin_bit_cast(int, f.y);
                    rank += ((dj < d) || (dj == d && ij < idx)) ? 1 : 0;
                }
                if (rank < 16) {
                    part_d[pb + rank] = d;
                    part_i[pb + rank] = idx;
                }
            }
        }
    } else {
        // ================= PROJ branch (R10 numerics, 32 pts/block) ======
        float (*fl)[3]   = sm.p.fl;
        float (*xl)[128] = sm.p.xl;

        const int tc = t & 127;               // channel 0..127
        const int pg = t >> 7;                // point-group 0..3
        const long base = (long)(blockIdx.x - 512) * 32 + pg * 8;

        if (tc < 24) {
            int p = tc / 3, d = tc % 3;
            long pt = base + p;
            int b = (int)(pt >> 13), n = (int)(pt & 8191);
            fl[pg*8 + p][d] = feat[((long)b * 3 + d) * NPTS + n];
        }
        __syncthreads();

        float w0 = fc1_w[tc*3+0], w1 = fc1_w[tc*3+1], w2 = fc1_w[tc*3+2];
        float b0 = fc1_b[tc];
        #pragma unroll
        for (int p = 0; p < 8; ++p)
            xl[pg*8 + p][tc] = fmaf(w0, fl[pg*8+p][0],
                               fmaf(w1, fl[pg*8+p][1],
                               fmaf(w2, fl[pg*8+p][2], b0)));
        __syncthreads();

        float aq[8], ak[8], av[8];
        #pragma unroll
        for (int p = 0; p < 8; ++p) { aq[p] = 0.f; ak[p] = 0.f; av[p] = 0.f; }

        for (int i4 = 0; i4 < 32; ++i4) {
            const int k0 = i4 * 4;
            float qa = wqT[(k0+0)*128 + tc], qbw = wqT[(k0+1)*128 + tc];
            float qc2 = wqT[(k0+2)*128 + tc], qd = wqT[(k0+3)*128 + tc];
            float ka = wkT[(k0+0)*128 + tc], kbw = wkT[(k0+1)*128 + tc];
            float kc2 = wkT[(k0+2)*128 + tc], kd = wkT[(k0+3)*128 + tc];
            float va = wvT[(k0+0)*128 + tc], vbw = wvT[(k0+1)*128 + tc];
            float vc2 = wvT[(k0+2)*128 + tc], vd = wvT[(k0+3)*128 + tc];
            #pragma unroll
            for (int p = 0; p < 8; ++p) {
                float4 x = *(const float4*)&xl[pg*8 + p][k0];
                aq[p] = fmaf(qa,x.x, fmaf(qbw,x.y, fmaf(qc2,x.z, fmaf(qd,x.w, aq[p]))));
                ak[p] = fmaf(ka,x.x, fmaf(kbw,x.y, fmaf(kc2,x.z, fmaf(kd,x.w, ak[p]))));
                av[p] = fmaf(va,x.x, fmaf(vbw,x.y, fmaf(vc2,x.z, fmaf(vd,x.w, av[p]))));
            }
        }
        const int perm = (tc & 15) * 8 + (tc >> 4);
        #pragma unroll
        for (int p = 0; p < 8; ++p) {
            long pt = base + p;
            qb[pt*128 + perm]   = f2bf(aq[p]);
            kbuf[pt*128 + perm] = f2bf(ak[p]);
            vbuf[pt*128 + perm] = f2bf(av[p]);
        }
    }
}

// ---------------------------------------------------------------------------
// Kernel 2: merge 2 partial top-16 -> final top-16 (R11/R18 verbatim)
// ---------------------------------------------------------------------------
__global__ __launch_bounds__(256, 4)
void knn_merge_kernel(const float* __restrict__ part_d,
                      const int* __restrict__ part_i, int* __restrict__ knn)
{
    __shared__ float sd[8][33];
    __shared__ int   si[8][33];
    const int t = threadIdx.x;
    const int qq = t >> 5, e = t & 31;
    const long q = (long)blockIdx.x * 8 + qq;
    float d = part_d[q * 32 + e];
    int idx = part_i[q * 32 + e];
    sd[qq][e] = d; si[qq][e] = idx;
    __syncthreads();
    int rank = 0;
    #pragma unroll
    for (int j = 0; j < 32; ++j) {
        float dj = sd[qq][j];
        rank += ((dj < d) || (dj == d && si[qq][j] < idx)) ? 1 : 0;
    }
    if (rank < 16) knn[q * 16 + rank] = idx;
}

// ---------------------------------------------------------------------------
// Kernel 3: fused attention v9 (R18 verbatim — 4-wave-packed, LDS-staged
// weights; attn < 111us proven).
// ---------------------------------------------------------------------------
__device__ inline int hswz(int r, int c) {           // hbuf swizzled index
    return r * 128 + (c ^ ((r & 7) << 4));
}
__device__ inline int wswz(int r, int c) {           // wbuf swizzled index
    return r * 128 + (c ^ ((r & 7) << 3));
}

__global__ __launch_bounds__(256, 2)
void attn_kernel(const float* __restrict__ xyz, const float* __restrict__ feat,
                 const float* __restrict__ d1_w, const float* __restrict__ d1_b,
                 const float* __restrict__ d2_b, const float* __restrict__ g1_b,
                 const float* __restrict__ g2_b,
                 const float* __restrict__ fc2_w, const float* __restrict__ fc2_b,
                 const unsigned short* __restrict__ qb,
                 const unsigned short* __restrict__ kb,
                 const unsigned short* __restrict__ vb,
                 const unsigned short* __restrict__ wd2,
                 const unsigned short* __restrict__ wg1,
                 const unsigned short* __restrict__ wg2,
                 const int* __restrict__ knn, float* __restrict__ out)
{
    __shared__ unsigned short hbuf_all[4][32 * 128];  // per-wave private slice
    __shared__ unsigned short wbuf[128 * 128];        // shared weight stage

    const int wave = threadIdx.x >> 6;
    const int lane = threadIdx.x & 63;
    unsigned short* hbuf = hbuf_all[wave];

    const int quad = lane >> 4, l15 = lane & 15;
    const long pbase = (long)blockIdx.x * 8 + wave * 2;
    const int b = (int)(pbase >> 13);
    const long bofs = (long)b * NPTS;

    auto stageW = [&](const unsigned short* w) {
        #pragma unroll
        for (int it = 0; it < 8; ++it) {
            int cidx = (int)threadIdx.x + it * 256;   // 0..2047
            int row = cidx >> 4, c8 = (cidx & 15) << 3;
            short8 v = *(const short8*)(w + cidx * 8);
            *(short8*)&wbuf[wswz(row, c8)] = v;
        }
    };

    // lanes<32: neighbor index + rel vector for row `lane`
    int m = 0; float rx = 0.f, ry = 0.f, rz = 0.f;
    if (lane < 32) {
        m = knn[(pbase + (lane >> 4)) * 16 + (lane & 15)];
        int nn = (int)((pbase + (lane >> 4)) & 8191);
        const float* xg = xyz + (long)b * 3 * NPTS;
        rx = xg[nn]        - xg[m];
        ry = xg[NPTS+nn]   - xg[NPTS+m];
        rz = xg[2*NPTS+nn] - xg[2*NPTS+m];
    }

    // per-lane gather offsets into kb/vb (u16 elements), via shuffle
    int koff[8];
    #pragma unroll
    for (int mt = 0; mt < 2; ++mt)
        #pragma unroll
        for (int r = 0; r < 4; ++r) {
            int idxm = __shfl(m, mt*16 + quad*4 + r);
            koff[mt*4 + r] = (int)(bofs + idxm) * 128 + l15*8;
        }

    // K gather + q load early
    short8 qvv[2], kgv[2][4], vgv[2][4];
    #pragma unroll
    for (int mt = 0; mt < 2; ++mt) {
        qvv[mt] = *(const short8*)(qb + (size_t)(pbase + mt) * 128 + l15*8);
        #pragma unroll
        for (int r = 0; r < 4; ++r)
            kgv[mt][r] = *(const short8*)(kb + koff[mt*4 + r]);
    }

    // stage wd2 while gathers are in flight
    stageW(wd2);

    // h1 = relu(rel @ d1.T + b)
    {
        float w0[8], w1[8], w2[8], bb[8];
        #pragma unroll
        for (int k = 0; k < 8; ++k) {
            int c = l15*8 + k;
            w0[k] = d1_w[c*3]; w1[k] = d1_w[c*3+1]; w2[k] = d1_w[c*3+2];
            bb[k] = d1_b[c];
        }
        #pragma unroll
        for (int i = 0; i < 8; ++i) {
            int row = quad + 4*i;
            float sx = __shfl(rx, row), sy = __shfl(ry, row), sz = __shfl(rz, row);
            short8 hv;
            #pragma unroll
            for (int k = 0; k < 8; ++k) {
                float v = fmaf(w0[k], sx, fmaf(w1[k], sy, fmaf(w2[k], sz, bb[k])));
                hv[k] = (short)f2bf(fmaxf(v, 0.f));
            }
            *(short8*)&hbuf[hswz(row, l15*8)] = hv;
        }
    }
    __syncthreads();   // wd2 staged + h1 written

    short8 A[2][4];
    f32x4 acc[2];

    auto loadA = [&]() {
        #pragma unroll
        for (int mt = 0; mt < 2; ++mt)
            #pragma unroll
            for (int kk = 0; kk < 4; ++kk)
                A[mt][kk] = *(const short8*)&hbuf[hswz(mt*16 + l15, kk*32 + quad*8)];
    };
    auto loadB = [&](int n0, short8& B0, short8& B1, short8& B2, short8& B3) {
        int r = n0*16 + l15;
        B0 = *(const short8*)&wbuf[wswz(r, quad*8)];
        B1 = *(const short8*)&wbuf[wswz(r, quad*8 + 32)];
        B2 = *(const short8*)&wbuf[wswz(r, quad*8 + 64)];
        B3 = *(const short8*)&wbuf[wswz(r, quad*8 + 96)];
    };

    unsigned posp[2][8][2];   // packed bf16 pos fragments

    // ============ GEMM 1: pos = h1 @ d2.T + b; h = q - kg + pos ============
    loadA();
    #pragma unroll
    for (int n0 = 0; n0 < 8; ++n0) {
        short8 B0, B1, B2, B3;
        loadB(n0, B0, B1, B2, B3);
        acc[0] = (f32x4){0.f,0.f,0.f,0.f};
        acc[1] = (f32x4){0.f,0.f,0.f,0.f};
        __builtin_amdgcn_s_setprio(1);
        #pragma unroll
        for (int mt = 0; mt < 2; ++mt) {
            acc[mt] = __builtin_amdgcn_mfma_f32_16x16x32_bf16(A[mt][0], B0, acc[mt], 0, 0, 0);
            acc[mt] = __builtin_amdgcn_mfma_f32_16x16x32_bf16(A[mt][1], B1, acc[mt], 0, 0, 0);
            acc[mt] = __builtin_amdgcn_mfma_f32_16x16x32_bf16(A[mt][2], B2, acc[mt], 0, 0, 0);
            acc[mt] = __builtin_amdgcn_mfma_f32_16x16x32_bf16(A[mt][3], B3, acc[mt], 0, 0, 0);
        }
        __builtin_amdgcn_s_setprio(0);
        int c = n0*16 + l15;
        float bb = d2_b[c];
        #pragma unroll
        for (int mt = 0; mt < 2; ++mt) {
            float qv = bf2f((unsigned short)qvv[mt][n0]);
            float p0 = acc[mt][0] + bb, p1 = acc[mt][1] + bb;
            float p2 = acc[mt][2] + bb, p3 = acc[mt][3] + bb;
            posp[mt][n0][0] = (unsigned)f2bf(p0) | ((unsigned)f2bf(p1) << 16);
            posp[mt][n0][1] = (unsigned)f2bf(p2) | ((unsigned)f2bf(p3) << 16);
            int rb = mt*16 + quad*4;
            hbuf[hswz(rb+0, c)] = f2bf(qv - bf2f((unsigned short)kgv[mt][0][n0]) + p0);
            hbuf[hswz(rb+1, c)] = f2bf(qv - bf2f((unsigned short)kgv[mt][1][n0]) + p1);
            hbuf[hswz(rb+2, c)] = f2bf(qv - bf2f((unsigned short)kgv[mt][2][n0]) + p2);
            hbuf[hswz(rb+3, c)] = f2bf(qv - bf2f((unsigned short)kgv[mt][3][n0]) + p3);
        }
    }
    __syncthreads();          // all waves done reading wd2
    stageW(wg1);
    __syncthreads();          // wg1 staged

    // ============ GEMM 2: gh = relu(h @ g1.T + b) ============
    loadA();
    #pragma unroll
    for (int n0 = 0; n0 < 8; ++n0) {
        short8 B0, B1, B2, B3;
        loadB(n0, B0, B1, B2, B3);
        acc[0] = (f32x4){0.f,0.f,0.f,0.f};
        acc[1] = (f32x4){0.f,0.f,0.f,0.f};
        __builtin_amdgcn_s_setprio(1);
        #pragma unroll
        for (int mt = 0; mt < 2; ++mt) {
            acc[mt] = __builtin_amdgcn_mfma_f32_16x16x32_bf16(A[mt][0], B0, acc[mt], 0, 0, 0);
            acc[mt] = __builtin_amdgcn_mfma_f32_16x16x32_bf16(A[mt][1], B1, acc[mt], 0, 0, 0);
            acc[mt] = __builtin_amdgcn_mfma_f32_16x16x32_bf16(A[mt][2], B2, acc[mt], 0, 0, 0);
            acc[mt] = __builtin_amdgcn_mfma_f32_16x16x32_bf16(A[mt][3], B3, acc[mt], 0, 0, 0);
        }
        __builtin_amdgcn_s_setprio(0);
        int c = n0*16 + l15;
        float bb = g1_b[c];
        #pragma unroll
        for (int mt = 0; mt < 2; ++mt) {
            int rb = mt*16 + quad*4;
            #pragma unroll
            for (int r = 0; r < 4; ++r)
                hbuf[hswz(rb+r, c)] = f2bf(fmaxf(acc[mt][r] + bb, 0.f));
        }
    }
    __syncthreads();          // all waves done reading wg1
    stageW(wg2);

    // deferred V gather (only needed by GEMM 3)
    #pragma unroll
    for (int mt = 0; mt < 2; ++mt)
        #pragma unroll
        for (int r = 0; r < 4; ++r)
            vgv[mt][r] = *(const short8*)(vb + koff[mt*4 + r]);
    __syncthreads();          // wg2 staged

    // ==== GEMM 3: logits -> softmax over K -> res -> fused fc2 epilogue ====
    loadA();
    const float sc = 0.08838834764831845f;
    float pr[2][3];
    #pragma unroll
    for (int mt = 0; mt < 2; ++mt) { pr[mt][0] = 0.f; pr[mt][1] = 0.f; pr[mt][2] = 0.f; }
    #pragma unroll
    for (int n0 = 0; n0 < 8; ++n0) {
        short8 B0, B1, B2, B3;
        loadB(n0, B0, B1, B2, B3);
        acc[0] = (f32x4){0.f,0.f,0.f,0.f};
        acc[1] = (f32x4){0.f,0.f,0.f,0.f};
        __builtin_amdgcn_s_setprio(1);
        #pragma unroll
        for (int mt = 0; mt < 2; ++mt) {
            acc[mt] = __builtin_amdgcn_mfma_f32_16x16x32_bf16(A[mt][0], B0, acc[mt], 0, 0, 0);
            acc[mt] = __builtin_amdgcn_mfma_f32_16x16x32_bf16(A[mt][1], B1, acc[mt], 0, 0, 0);
            acc[mt] = __builtin_amdgcn_mfma_f32_16x16x32_bf16(A[mt][2], B2, acc[mt], 0, 0, 0);
            acc[mt] = __builtin_amdgcn_mfma_f32_16x16x32_bf16(A[mt][3], B3, acc[mt], 0, 0, 0);
        }
        __builtin_amdgcn_s_setprio(0);
        int c = n0*16 + l15;
        float bb = g2_b[c];
        float f0 = fc2_w[c];
        float f1 = fc2_w[128 + c];
        float f2 = fc2_w[256 + c];
        #pragma unroll
        for (int mt = 0; mt < 2; ++mt) {
            float e0 = (acc[mt][0] + bb) * sc;
            float e1 = (acc[mt][1] + bb) * sc;
            float e2 = (acc[mt][2] + bb) * sc;
            float e3 = (acc[mt][3] + bb) * sc;
            float mx = fmaxf(fmaxf(e0, e1), fmaxf(e2, e3));
            mx = fmaxf(mx, __shfl_xor(mx, 16));
            mx = fmaxf(mx, __shfl_xor(mx, 32));
            e0 = __expf(e0 - mx); e1 = __expf(e1 - mx);
            e2 = __expf(e2 - mx); e3 = __expf(e3 - mx);
            float ssum = e0 + e1 + e2 + e3;
            ssum += __shfl_xor(ssum, 16);
            ssum += __shfl_xor(ssum, 32);
            float p0 = bf2f((unsigned short)(posp[mt][n0][0] & 0xffff));
            float p1 = bf2f((unsigned short)(posp[mt][n0][0] >> 16));
            float p2 = bf2f((unsigned short)(posp[mt][n0][1] & 0xffff));
            float p3 = bf2f((unsigned short)(posp[mt][n0][1] >> 16));
            float p = e0 * (bf2f((unsigned short)vgv[mt][0][n0]) + p0)
                    + e1 * (bf2f((unsigned short)vgv[mt][1][n0]) + p1)
                    + e2 * (bf2f((unsigned short)vgv[mt][2][n0]) + p2)
                    + e3 * (bf2f((unsigned short)vgv[mt][3][n0]) + p3);
            p += __shfl_xor(p, 16);
            p += __shfl_xor(p, 32);
            float rres = p / ssum;                 // replicated across quads
            pr[mt][0] = fmaf(f0, rres, pr[mt][0]);
            pr[mt][1] = fmaf(f1, rres, pr[mt][1]);
            pr[mt][2] = fmaf(f2, rres, pr[mt][2]);
        }
    }

    // reduce fc2 partials over l15 (quads are replicas) and store
    #pragma unroll
    for (int mt = 0; mt < 2; ++mt) {
        float pr0 = pr[mt][0], pr1 = pr[mt][1], pr2 = pr[mt][2];
        #pragma unroll
        for (int s2 = 1; s2 <= 8; s2 <<= 1) {
            pr0 += __shfl_xor(pr0, s2);
            pr1 += __shfl_xor(pr1, s2);
            pr2 += __shfl_xor(pr2, s2);
        }
        int nn = (int)((pbase + mt) & 8191);
        if (lane < 3) {
            float pv = (lane == 0) ? pr0 : (lane == 1) ? pr1 : pr2;
            long o = ((long)b*3 + lane) * NPTS + nn;
            out[o] = pv + fc2_b[lane] + feat[o];
        }
    }
}

// ---------------------------------------------------------------------------
extern "C" void kernel_launch(void* const* d_in, const int* in_sizes, int n_in,
                              void* d_out, int out_size, void* d_ws, size_t ws_size,
                              hipStream_t stream)
{
    const float* xyz   = (const float*)d_in[0];
    const float* feat  = (const float*)d_in[1];
    const float* fc1_w = (const float*)d_in[2];
    const float* fc1_b = (const float*)d_in[3];
    const float* fc2_w = (const float*)d_in[4];
    const float* fc2_b = (const float*)d_in[5];
    const float* d1_w  = (const float*)d_in[6];
    const float* d1_b  = (const float*)d_in[7];
    const float* d2_w  = (const float*)d_in[8];
    const float* d2_b  = (const float*)d_in[9];
    const float* g1_w  = (const float*)d_in[10];
    const float* g1_b  = (const float*)d_in[11];
    const float* g2_w  = (const float*)d_in[12];
    const float* g2_b  = (const float*)d_in[13];
    const float* wq_w  = (const float*)d_in[14];
    const float* wk_w  = (const float*)d_in[15];
    const float* wv_w  = (const float*)d_in[16];
    float* out = (float*)d_out;

    unsigned short* qb  = (unsigned short*)d_ws;      // 16384*128 bf16 (permuted)
    unsigned short* kb  = qb + (size_t)16384*128;
    unsigned short* vb  = kb + (size_t)16384*128;
    unsigned short* wd2 = vb + (size_t)16384*128;     // 128*128 bf16 each
    unsigned short* wg1 = wd2 + 16384;
    unsigned short* wg2 = wg1 + 16384;
    int*   knn_ws = (int*)(wg2 + 16384);              // 16384*16 i32
    float4* cand  = (float4*)(knn_ws + (size_t)16384*16);   // 16384 float4
    float* part_d = (float*)(cand + 16384);           // [0, 16384*32) used by knn
    int*   part_i = (int*)(part_d + (size_t)16384*64);// [0, 16384*32) used by knn
    // wqT/wkT/wvT live in the UNUSED upper half of part_d — no extension.
    float* wqT    = part_d + (size_t)16384*32;        // 128*128 f32 each
    float* wkT    = wqT + 16384;
    float* wvT    = wkT + 16384;

    hipLaunchKernelGGL(prep_kernel, dim3(448), dim3(256), 0, stream,
                       d2_w, g1_w, g2_w, wd2, wg1, wg2, xyz, cand,
                       wq_w, wk_w, wv_w, wqT, wkT, wvT);
    hipLaunchKernelGGL(knn_proj_kernel, dim3(1024), dim3(512), 0, stream,
                       cand, part_d, part_i,
                       feat, fc1_w, fc1_b, wqT, wkT, wvT, qb, kb, vb);
    hipLaunchKernelGGL(knn_merge_kernel, dim3(2048), dim3(256), 0, stream,
                       part_d, part_i, knn_ws);
    hipLaunchKernelGGL(attn_kernel, dim3(2048), dim3(256), 0, stream,
                       xyz, feat, d1_w, d1_b, d2_b, g1_b, g2_b, fc2_w, fc2_b,
                       qb, kb, vb, wd2, wg1, wg2, knn_ws, out);
}